// Round 17
// baseline (172.303 us; speedup 1.0000x reference)
//
#include <hip/hip_runtime.h>
#include <hip/hip_fp16.h>
#include <math.h>
#include <stdint.h>

static constexpr int kN     = 50000;
static constexpr int kFIn   = 128;
static constexpr int kHeads = 4;
static constexpr int kScanB = 256;
static constexpr int kScanNB = (kN + kScanB - 1) / kScanB;   // 196

typedef _Float16 half8v  __attribute__((ext_vector_type(8)));
typedef float    floatx4 __attribute__((ext_vector_type(4)));

__device__ __forceinline__ float lrelu(float x) { return x > 0.f ? x : 0.2f * x; }

// value-level (address-free) pack of 2 floats -> 2 halves in a float's bits
__device__ __forceinline__ float pack2h(float a, float b) {
    const __half2 h = __floats2half2_rn(a, b);
    return __uint_as_float(__builtin_bit_cast(uint32_t, h));
}

// ---- init: zero deg ----
__global__ void k_init(int* __restrict__ p, int n) {
    int i = blockIdx.x * blockDim.x + threadIdx.x;
    if (i < n) p[i] = 0;
}

// ---- layer 1 node transform via MFMA: h1 = fp16(x) @ fp16(W1), f32 accum. ----
__global__ __launch_bounds__(256)
void k_gemm1(const float* __restrict__ x, const float* __restrict__ W1,
             __half* __restrict__ h1h, int nPass, int grid) {
    __shared__ __align__(16) float whf[128 * 16 * 4];  // 32 KB (fp16 W1, rotated granules)
    __shared__ __align__(16) float xsf[32 * 16 * 4];   //  8 KB (fp16 x tile, rotated granules)
    const int t = threadIdx.x;
    const int l = t & 63;
    const int g = t >> 6;                            // wave 0..3
    for (int idx = t; idx < 2048; idx += 256) {
        const int c = idx >> 7, col = idx & 127;
        float4 st;
        st.x = pack2h(W1[(8 * c + 0) * 128 + col], W1[(8 * c + 1) * 128 + col]);
        st.y = pack2h(W1[(8 * c + 2) * 128 + col], W1[(8 * c + 3) * 128 + col]);
        st.z = pack2h(W1[(8 * c + 4) * 128 + col], W1[(8 * c + 5) * 128 + col]);
        st.w = pack2h(W1[(8 * c + 6) * 128 + col], W1[(8 * c + 7) * 128 + col]);
        const int gran = col * 16 + ((c + col) & 15);
        *reinterpret_cast<float4*>(&whf[gran * 4]) = st;
    }
    __syncthreads();

    const int rt  = g & 1;
    const int ctB = (g >> 1) * 4;
    const int lm  = l & 15;
    const int lk  = l >> 4;

    for (int pass = blockIdx.x; pass < nPass; pass += grid) {
        const int nodeBase = pass * 32;
        for (int q = t; q < 512; q += 256) {
            const int nn = q >> 4, ck = q & 15;
            int n = nodeBase + nn; if (n >= kN) n = kN - 1;
            const float4 xa = *reinterpret_cast<const float4*>(&x[(size_t)n * 128 + ck * 8]);
            const float4 xb = *reinterpret_cast<const float4*>(&x[(size_t)n * 128 + ck * 8 + 4]);
            float4 st;
            st.x = pack2h(xa.x, xa.y);
            st.y = pack2h(xa.z, xa.w);
            st.z = pack2h(xb.x, xb.y);
            st.w = pack2h(xb.z, xb.w);
            const int gran = nn * 16 + ((ck + nn) & 15);
            *reinterpret_cast<float4*>(&xsf[gran * 4]) = st;
        }
        __syncthreads();

        floatx4 acc0 = {0.f, 0.f, 0.f, 0.f};
        floatx4 acc1 = {0.f, 0.f, 0.f, 0.f};
        floatx4 acc2 = {0.f, 0.f, 0.f, 0.f};
        floatx4 acc3 = {0.f, 0.f, 0.f, 0.f};
        const int node = rt * 16 + lm;
        const int ch0  = ctB * 16 + lm;
#pragma unroll
        for (int kk = 0; kk < 4; ++kk) {
            const int ck = lk + 4 * kk;
            const half8v af = *reinterpret_cast<const half8v*>(
                &xsf[(node * 16 + ((ck + node) & 15)) * 4]);
            const half8v b0 = *reinterpret_cast<const half8v*>(
                &whf[((ch0 +  0) * 16 + ((ck + ch0 +  0) & 15)) * 4]);
            const half8v b1 = *reinterpret_cast<const half8v*>(
                &whf[((ch0 + 16) * 16 + ((ck + ch0 + 16) & 15)) * 4]);
            const half8v b2 = *reinterpret_cast<const half8v*>(
                &whf[((ch0 + 32) * 16 + ((ck + ch0 + 32) & 15)) * 4]);
            const half8v b3 = *reinterpret_cast<const half8v*>(
                &whf[((ch0 + 48) * 16 + ((ck + ch0 + 48) & 15)) * 4]);
            acc0 = __builtin_amdgcn_mfma_f32_16x16x32_f16(af, b0, acc0, 0, 0, 0);
            acc1 = __builtin_amdgcn_mfma_f32_16x16x32_f16(af, b1, acc1, 0, 0, 0);
            acc2 = __builtin_amdgcn_mfma_f32_16x16x32_f16(af, b2, acc2, 0, 0, 0);
            acc3 = __builtin_amdgcn_mfma_f32_16x16x32_f16(af, b3, acc3, 0, 0, 0);
        }
        const int nrow0 = nodeBase + rt * 16 + lk * 4;
#pragma unroll
        for (int r = 0; r < 4; ++r) {
            const int n = nrow0 + r;
            if (n < kN) {
                h1h[(size_t)n * 128 + ch0     ] = __float2half(acc0[r]);
                h1h[(size_t)n * 128 + ch0 + 16] = __float2half(acc1[r]);
                h1h[(size_t)n * 128 + ch0 + 32] = __float2half(acc2[r]);
                h1h[(size_t)n * 128 + ch0 + 48] = __float2half(acc3[r]);
            }
        }
        __syncthreads();
    }
}

// ---- attention logits from h1 (fp16): one wave per node, lane = 2 channels ----
__global__ __launch_bounds__(256)
void k_logits(const __half* __restrict__ h1h,
              const float* __restrict__ a_src1, const float* __restrict__ a_dst1,
              float* __restrict__ asrc, float* __restrict__ adst) {
    const int n = blockIdx.x * 4 + (threadIdx.x >> 6);
    if (n >= kN) return;
    const int j = threadIdx.x & 63;
    const float2 f = __half22float2(*(const __half2*)&h1h[(size_t)n * 128 + 2 * j]);
    float ps = f.x * a_src1[2 * j] + f.y * a_src1[2 * j + 1];
    float pd = f.x * a_dst1[2 * j] + f.y * a_dst1[2 * j + 1];
#pragma unroll
    for (int off = 8; off >= 1; off >>= 1) {
        ps += __shfl_xor(ps, off, 64);
        pd += __shfl_xor(pd, off, 64);
    }
    if ((j & 15) == 0) {
        asrc[n * 4 + (j >> 4)] = ps;
        adst[n * 4 + (j >> 4)] = pd;
    }
}

// ---- CSR build ----
__global__ void k_hist(const int* __restrict__ ei, int E, int* __restrict__ deg,
                       int* __restrict__ rank) {
    int i = blockIdx.x * blockDim.x + threadIdx.x;
    int total = E + kN;
    if (i >= total) return;
    int d = (i < E) ? ei[E + i] : (i - E);
    rank[i] = atomicAdd(&deg[d], 1);
}

__global__ void k_scan_a(const int* __restrict__ deg, int* __restrict__ loc, int* __restrict__ bsum) {
    __shared__ int tmp[kScanB];
    int t = threadIdx.x;
    int i = blockIdx.x * kScanB + t;
    int v = (i < kN) ? deg[i] : 0;
    tmp[t] = v;
    __syncthreads();
    for (int off = 1; off < kScanB; off <<= 1) {
        int add = (t >= off) ? tmp[t - off] : 0;
        __syncthreads();
        tmp[t] += add;
        __syncthreads();
    }
    if (i < kN) loc[i] = tmp[t] - v;
    if (t == kScanB - 1) bsum[blockIdx.x] = tmp[t];
}

__global__ void k_scan_b(int* __restrict__ bsum) {
    __shared__ int tmp[256];
    int t = threadIdx.x;
    int v = (t < kScanNB) ? bsum[t] : 0;
    tmp[t] = v;
    __syncthreads();
    for (int off = 1; off < 256; off <<= 1) {
        int add = (t >= off) ? tmp[t - off] : 0;
        __syncthreads();
        tmp[t] += add;
        __syncthreads();
    }
    if (t < kScanNB) bsum[t] = tmp[t] - v;
}

__global__ void k_scan_c(const int* __restrict__ loc, const int* __restrict__ bsum,
                         int* __restrict__ rowptr, int E2) {
    int i = blockIdx.x * kScanB + threadIdx.x;
    if (i < kN) rowptr[i] = loc[i] + bsum[blockIdx.x];
    if (i == 0) rowptr[kN] = E2;
}

// ---- scatter: pure permutation write (4B per edge), no atomic ----
__global__ void k_scatter(const int* __restrict__ ei, int E,
                          const int* __restrict__ rowptr, const int* __restrict__ rank,
                          int* __restrict__ es) {
    int i = blockIdx.x * blockDim.x + threadIdx.x;
    int total = E + kN;
    if (i >= total) return;
    int s, d;
    if (i < E) { s = ei[i]; d = ei[E + i]; } else { s = d = i - E; }
    es[rowptr[d] + rank[i]] = s;
}

// ---- normalized fp16 alpha in CSR order (R16 verified) ----
__global__ __launch_bounds__(256)
void k_wgt(const int* __restrict__ rowptr, const int* __restrict__ es,
           const float* __restrict__ asrc, const float* __restrict__ adst,
           __half* __restrict__ alphaH) {
    const int n = blockIdx.x * 16 + (threadIdx.x >> 4);
    if (n >= kN) return;
    const int l = threadIdx.x & 15;
    const int beg = rowptr[n], end = rowptr[n + 1];
    const float ad0 = adst[n * 4 + 0], ad1 = adst[n * 4 + 1];
    const float ad2 = adst[n * 4 + 2], ad3 = adst[n * 4 + 3];
    float t0 = 0.f, t1 = 0.f, t2 = 0.f, t3 = 0.f;
    for (int p = beg + l; p < end; p += 16) {
        const int s = es[p];
        t0 += expf(lrelu(asrc[s * 4 + 0] + ad0));
        t1 += expf(lrelu(asrc[s * 4 + 1] + ad1));
        t2 += expf(lrelu(asrc[s * 4 + 2] + ad2));
        t3 += expf(lrelu(asrc[s * 4 + 3] + ad3));
    }
#pragma unroll
    for (int off = 8; off >= 1; off >>= 1) {
        t0 += __shfl_xor(t0, off, 64);
        t1 += __shfl_xor(t1, off, 64);
        t2 += __shfl_xor(t2, off, 64);
        t3 += __shfl_xor(t3, off, 64);
    }
    const float r0 = 1.f / t0, r1 = 1.f / t1, r2 = 1.f / t2, r3 = 1.f / t3;
    for (int p = beg + l; p < end; p += 16) {
        const int s = es[p];
        const float w0 = expf(lrelu(asrc[s * 4 + 0] + ad0)) * r0;
        const float w1 = expf(lrelu(asrc[s * 4 + 1] + ad1)) * r1;
        const float w2 = expf(lrelu(asrc[s * 4 + 2] + ad2)) * r2;
        const float w3 = expf(lrelu(asrc[s * 4 + 3] + ad3)) * r3;
        float2 st;
        st.x = pack2h(w0, w1);
        st.y = pack2h(w2, w3);
        *reinterpret_cast<float2*>(&alphaH[(size_t)p * 4]) = st;
    }
}

// ---- layer 1 aggregation, HEAD-SPLIT + XCD-pinned: head = (blockIdx&7)>>1 so
//      each XCD's L2 (4 MB) holds ONE head's h1 slice (3.2 MB) -> gathers become
//      L2-hits (R16: random full-row gathers streamed 116 MB through every L2).
//      Wave = 4 nodes x 16 lanes; per edge: 64 B coalesced head-slice gather +
//      one hfma2. Partials [4][N][32] fp16. Correct under ANY block->XCD mapping.
__global__ __launch_bounds__(256)
void k_agg1h(const int* __restrict__ rowptr, const int* __restrict__ es,
             const __half* __restrict__ alphaH, const __half* __restrict__ h1h,
             __half2* __restrict__ part) {
    const int b    = blockIdx.x;
    const int head = (b & 7) >> 1;                   // XCD pair -> head
    const int rank = (b >> 3) * 2 + (b & 1);         // chunk within head
    const int g    = threadIdx.x >> 6;
    const int l    = threadIdx.x & 63;
    const int sub  = l >> 4;                         // node within wave
    const int m    = l & 15;                         // channel pair within head
    const int n    = rank * 16 + g * 4 + sub;
    if (n >= kN) return;
    const int beg = rowptr[n], end = rowptr[n + 1];
    const __half2* h12 = (const __half2*)h1h;        // node stride 64 half2
    const int chOff = head * 16 + m;
    __half2 accA = __floats2half2_rn(0.f, 0.f);
    __half2 accB = __floats2half2_rn(0.f, 0.f);
    int p = beg;
    for (; p + 2 <= end; p += 2) {
        const int s0 = es[p], s1 = es[p + 1];
        const __half a0 = alphaH[(size_t)p * 4 + head];
        const __half a1 = alphaH[(size_t)(p + 1) * 4 + head];
        accA = __hfma2(__half2half2(a0), h12[(size_t)s0 * 64 + chOff], accA);
        accB = __hfma2(__half2half2(a1), h12[(size_t)s1 * 64 + chOff], accB);
    }
    if (p < end) {
        const int s0 = es[p];
        const __half a0 = alphaH[(size_t)p * 4 + head];
        accA = __hfma2(__half2half2(a0), h12[(size_t)s0 * 64 + chOff], accA);
    }
    part[((size_t)head * kN + n) * 16 + m] = __hadd2(accA, accB);
}

// ---- finish: mean over heads + bias + ELU + layer-2 matvec -> h2[n] ----
__global__ __launch_bounds__(256)
void k_finish(const __half2* __restrict__ part, const float* __restrict__ b1,
              const float* __restrict__ W2, float* __restrict__ h2) {
    const int n = blockIdx.x * 16 + (threadIdx.x >> 4);
    if (n >= kN) return;
    const int m = threadIdx.x & 15;
    float sx = 0.f, sy = 0.f;
#pragma unroll
    for (int h = 0; h < kHeads; ++h) {
        const float2 v = __half22float2(part[((size_t)h * kN + n) * 16 + m]);
        sx += v.x; sy += v.y;
    }
    float u0 = 0.25f * sx + b1[2 * m];
    float u1 = 0.25f * sy + b1[2 * m + 1];
    u0 = u0 > 0.f ? u0 : expf(u0) - 1.f;
    u1 = u1 > 0.f ? u1 : expf(u1) - 1.f;
    float tsum = u0 * W2[2 * m] + u1 * W2[2 * m + 1];
    tsum += __shfl_xor(tsum, 8, 64);
    tsum += __shfl_xor(tsum, 4, 64);
    tsum += __shfl_xor(tsum, 2, 64);
    tsum += __shfl_xor(tsum, 1, 64);
    if (m == 0) h2[n] = tsum;
}

// ---- layer 2: 16 lanes per node, gather h2 (L2-resident), fused bias -> out ----
__global__ __launch_bounds__(256)
void k_agg2(const int* __restrict__ rowptr, const int* __restrict__ es,
            const float* __restrict__ h2,
            const float* __restrict__ a_s2, const float* __restrict__ a_d2,
            const float* __restrict__ b2, float* __restrict__ out) {
    const int n = blockIdx.x * 16 + (threadIdx.x >> 4);
    if (n >= kN) return;
    const int l = threadIdx.x & 15;
    const float as = a_s2[0], ad = a_d2[0];
    const int beg = rowptr[n], end = rowptr[n + 1];
    const float hd = h2[n] * ad;
    float sw = 0.f, swh = 0.f;
    for (int p = beg + l; p < end; p += 16) {
        float hs = h2[es[p]];
        float w = expf(lrelu(hs * as + hd));
        sw += w;
        swh += w * hs;
    }
#pragma unroll
    for (int off = 8; off >= 1; off >>= 1) {
        sw  += __shfl_xor(sw, off, 64);
        swh += __shfl_xor(swh, off, 64);
    }
    if (l == 0) out[n] = swh / sw + b2[0];
}

extern "C" void kernel_launch(void* const* d_in, const int* in_sizes, int n_in,
                              void* d_out, int out_size, void* d_ws, size_t ws_size,
                              hipStream_t stream) {
    const float* x      = (const float*)d_in[0];
    const int*   ei     = (const int*)d_in[1];
    const float* W1     = (const float*)d_in[3];
    const float* a_src1 = (const float*)d_in[4];
    const float* a_dst1 = (const float*)d_in[5];
    const float* b1     = (const float*)d_in[6];
    const float* W2     = (const float*)d_in[7];
    const float* a_src2 = (const float*)d_in[8];
    const float* a_dst2 = (const float*)d_in[9];
    const float* b2     = (const float*)d_in[10];
    float* out = (float*)d_out;

    const int E  = in_sizes[1] / 2;      // 800000
    const int E2 = E + kN;               // 850000

    // workspace layout (float offsets)
    float*   ws     = (float*)d_ws;
    float*   asrc   = ws;                         //   200,000 f
    float*   adst   = ws + 200000;                //   200,000 f
    float*   h2     = ws + 400000;                //    50,000 f
    __half*  h1h    = (__half*)(ws + 450000);     // 6,400,000 h = 3,200,000 f
    __half*  alphaH = (__half*)(ws + 3650000);    // 3,400,000 h = 1,700,000 f
    __half2* part   = (__half2*)(ws + 5350000);   // 3,200,000 h2... (4*50000*16 h2 = 12.8MB = 3,200,000 f)
    int*     ibase  = (int*)(ws + 8550000);
    int*     es     = ibase;                      //   850,000 i
    int*     deg    = ibase + 850000;             //    50,000 i
    int*     rank   = ibase + 900000;             //   850,000 i
    int*     loc    = ibase + 1750000;            //    50,000 i
    int*     rowptr = ibase + 1800000;            //    50,001 i
    int*     bsum   = ibase + 1850016;            //       256 i

    k_init<<<(kN + 255) / 256, 256, 0, stream>>>(deg, kN);

    k_hist<<<(E2 + 255) / 256, 256, 0, stream>>>(ei, E, deg, rank);
    k_scan_a<<<kScanNB, kScanB, 0, stream>>>(deg, loc, bsum);
    k_scan_b<<<1, 256, 0, stream>>>(bsum);
    k_scan_c<<<kScanNB, kScanB, 0, stream>>>(loc, bsum, rowptr, E2);

    {
        const int nPass = (kN + 31) / 32;        // 1563
        const int grid  = 782;
        k_gemm1<<<grid, 256, 0, stream>>>(x, W1, h1h, nPass, grid);
    }

    k_logits<<<(kN + 3) / 4, 256, 0, stream>>>(h1h, a_src1, a_dst1, asrc, adst);

    k_scatter<<<(E2 + 255) / 256, 256, 0, stream>>>(ei, E, rowptr, rank, es);

    k_wgt<<<(kN + 15) / 16, 256, 0, stream>>>(rowptr, es, asrc, adst, alphaH);

    {
        // 4 heads x 2 XCDs x 1563 chunks: head = (b&7)>>1 pins one head per XCD
        const int grid = 8 * 1563;               // 12504; rank up to 3126 covers 50016 nodes
        k_agg1h<<<grid, 256, 0, stream>>>(rowptr, es, alphaH, h1h, part);
    }

    k_finish<<<(kN + 15) / 16, 256, 0, stream>>>(part, b1, W2, h2);

    k_agg2<<<(kN + 15) / 16, 256, 0, stream>>>(rowptr, es, h2, a_src2, a_dst2, b2, out);
}

// Round 20
// 137.636 us; speedup vs baseline: 1.2519x; 1.2519x over previous
//
#include <hip/hip_runtime.h>
#include <hip/hip_fp16.h>
#include <math.h>
#include <stdint.h>

static constexpr int kN     = 50000;
static constexpr int kFIn   = 128;
static constexpr int kHeads = 4;
static constexpr int kScanB = 256;
static constexpr int kScanNB = (kN + kScanB - 1) / kScanB;   // 196
static constexpr int kGemmGrid = 782;                        // gemm-role blocks

typedef _Float16 half8v  __attribute__((ext_vector_type(8)));
typedef float    floatx4 __attribute__((ext_vector_type(4)));

__device__ __forceinline__ float lrelu(float x) { return x > 0.f ? x : 0.2f * x; }

// value-level (address-free) pack of 2 floats -> 2 halves in a float's bits
__device__ __forceinline__ float pack2h(float a, float b) {
    const __half2 h = __floats2half2_rn(a, b);
    return __uint_as_float(__builtin_bit_cast(uint32_t, h));
}

// ---- init: zero deg (must complete before the fat kernel's hist atomics) ----
__global__ void k_init(int* __restrict__ p, int n) {
    int i = blockIdx.x * blockDim.x + threadIdx.x;
    if (i < n) p[i] = 0;
}

// ---- FAT KERNEL: blocks [0,kGemmGrid) = MFMA gemm1 (exact R16 body);
//      blocks [kGemmGrid, ...) = edge histogram + rank (exact R16 k_hist body).
//      The two roles touch disjoint data; fusing only overlaps their execution
//      (R16 serialized them on the stream). Numerics byte-identical to R16.
//      (R18/R19 lesson: the fused-LOGITS variant failed refcheck twice with a
//      defect inspection couldn't find — logits stay a separate kernel.)
__global__ __launch_bounds__(256)
void k_gemm1_hist(const float* __restrict__ x, const float* __restrict__ W1,
                  __half* __restrict__ h1h, int nPass,
                  const int* __restrict__ ei, int E,
                  int* __restrict__ deg, int* __restrict__ rank) {
    __shared__ __align__(16) float whf[128 * 16 * 4];  // 32 KB (fp16 W1, rotated granules)
    __shared__ __align__(16) float xsf[32 * 16 * 4];   //  8 KB (fp16 x tile, rotated granules)

    if (blockIdx.x >= kGemmGrid) {                     // ---- hist role ----
        const int i = (blockIdx.x - kGemmGrid) * 256 + threadIdx.x;
        const int total = E + kN;
        if (i < total) {
            const int d = (i < E) ? ei[E + i] : (i - E);
            rank[i] = atomicAdd(&deg[d], 1);
        }
        return;
    }

    // ---- gemm role (exact R16 k_gemm1) ----
    const int t = threadIdx.x;
    const int l = t & 63;
    const int g = t >> 6;                            // wave 0..3
    for (int idx = t; idx < 2048; idx += 256) {
        const int c = idx >> 7, col = idx & 127;
        float4 st;
        st.x = pack2h(W1[(8 * c + 0) * 128 + col], W1[(8 * c + 1) * 128 + col]);
        st.y = pack2h(W1[(8 * c + 2) * 128 + col], W1[(8 * c + 3) * 128 + col]);
        st.z = pack2h(W1[(8 * c + 4) * 128 + col], W1[(8 * c + 5) * 128 + col]);
        st.w = pack2h(W1[(8 * c + 6) * 128 + col], W1[(8 * c + 7) * 128 + col]);
        const int gran = col * 16 + ((c + col) & 15);
        *reinterpret_cast<float4*>(&whf[gran * 4]) = st;
    }
    __syncthreads();

    const int rt  = g & 1;
    const int ctB = (g >> 1) * 4;
    const int lm  = l & 15;
    const int lk  = l >> 4;

    for (int pass = blockIdx.x; pass < nPass; pass += kGemmGrid) {
        const int nodeBase = pass * 32;
        for (int q = t; q < 512; q += 256) {
            const int nn = q >> 4, ck = q & 15;
            int n = nodeBase + nn; if (n >= kN) n = kN - 1;
            const float4 xa = *reinterpret_cast<const float4*>(&x[(size_t)n * 128 + ck * 8]);
            const float4 xb = *reinterpret_cast<const float4*>(&x[(size_t)n * 128 + ck * 8 + 4]);
            float4 st;
            st.x = pack2h(xa.x, xa.y);
            st.y = pack2h(xa.z, xa.w);
            st.z = pack2h(xb.x, xb.y);
            st.w = pack2h(xb.z, xb.w);
            const int gran = nn * 16 + ((ck + nn) & 15);
            *reinterpret_cast<float4*>(&xsf[gran * 4]) = st;
        }
        __syncthreads();

        floatx4 acc0 = {0.f, 0.f, 0.f, 0.f};
        floatx4 acc1 = {0.f, 0.f, 0.f, 0.f};
        floatx4 acc2 = {0.f, 0.f, 0.f, 0.f};
        floatx4 acc3 = {0.f, 0.f, 0.f, 0.f};
        const int node = rt * 16 + lm;
        const int ch0  = ctB * 16 + lm;
#pragma unroll
        for (int kk = 0; kk < 4; ++kk) {
            const int ck = lk + 4 * kk;
            const half8v af = *reinterpret_cast<const half8v*>(
                &xsf[(node * 16 + ((ck + node) & 15)) * 4]);
            const half8v b0 = *reinterpret_cast<const half8v*>(
                &whf[((ch0 +  0) * 16 + ((ck + ch0 +  0) & 15)) * 4]);
            const half8v b1 = *reinterpret_cast<const half8v*>(
                &whf[((ch0 + 16) * 16 + ((ck + ch0 + 16) & 15)) * 4]);
            const half8v b2 = *reinterpret_cast<const half8v*>(
                &whf[((ch0 + 32) * 16 + ((ck + ch0 + 32) & 15)) * 4]);
            const half8v b3 = *reinterpret_cast<const half8v*>(
                &whf[((ch0 + 48) * 16 + ((ck + ch0 + 48) & 15)) * 4]);
            acc0 = __builtin_amdgcn_mfma_f32_16x16x32_f16(af, b0, acc0, 0, 0, 0);
            acc1 = __builtin_amdgcn_mfma_f32_16x16x32_f16(af, b1, acc1, 0, 0, 0);
            acc2 = __builtin_amdgcn_mfma_f32_16x16x32_f16(af, b2, acc2, 0, 0, 0);
            acc3 = __builtin_amdgcn_mfma_f32_16x16x32_f16(af, b3, acc3, 0, 0, 0);
        }
        // D: col = lm, row = lk*4 + r
        const int nrow0 = nodeBase + rt * 16 + lk * 4;
#pragma unroll
        for (int r = 0; r < 4; ++r) {
            const int n = nrow0 + r;
            if (n < kN) {
                h1h[(size_t)n * 128 + ch0     ] = __float2half(acc0[r]);
                h1h[(size_t)n * 128 + ch0 + 16] = __float2half(acc1[r]);
                h1h[(size_t)n * 128 + ch0 + 32] = __float2half(acc2[r]);
                h1h[(size_t)n * 128 + ch0 + 48] = __float2half(acc3[r]);
            }
        }
        __syncthreads();
    }
}

// ---- attention logits from h1 (fp16): one wave per node, lane = 2 channels
//      (exact R16 k_logits — the verified-passing numeric path) ----
__global__ __launch_bounds__(256)
void k_logits(const __half* __restrict__ h1h,
              const float* __restrict__ a_src1, const float* __restrict__ a_dst1,
              float* __restrict__ asrc, float* __restrict__ adst) {
    const int n = blockIdx.x * 4 + (threadIdx.x >> 6);
    if (n >= kN) return;
    const int j = threadIdx.x & 63;
    const float2 f = __half22float2(*(const __half2*)&h1h[(size_t)n * 128 + 2 * j]);
    float ps = f.x * a_src1[2 * j] + f.y * a_src1[2 * j + 1];
    float pd = f.x * a_dst1[2 * j] + f.y * a_dst1[2 * j + 1];
#pragma unroll
    for (int off = 8; off >= 1; off >>= 1) {
        ps += __shfl_xor(ps, off, 64);
        pd += __shfl_xor(pd, off, 64);
    }
    if ((j & 15) == 0) {
        asrc[n * 4 + (j >> 4)] = ps;
        adst[n * 4 + (j >> 4)] = pd;
    }
}

__global__ void k_scan_a(const int* __restrict__ deg, int* __restrict__ loc, int* __restrict__ bsum) {
    __shared__ int tmp[kScanB];
    int t = threadIdx.x;
    int i = blockIdx.x * kScanB + t;
    int v = (i < kN) ? deg[i] : 0;
    tmp[t] = v;
    __syncthreads();
    for (int off = 1; off < kScanB; off <<= 1) {
        int add = (t >= off) ? tmp[t - off] : 0;
        __syncthreads();
        tmp[t] += add;
        __syncthreads();
    }
    if (i < kN) loc[i] = tmp[t] - v;
    if (t == kScanB - 1) bsum[blockIdx.x] = tmp[t];
}

__global__ void k_scan_b(int* __restrict__ bsum) {
    __shared__ int tmp[256];
    int t = threadIdx.x;
    int v = (t < kScanNB) ? bsum[t] : 0;
    tmp[t] = v;
    __syncthreads();
    for (int off = 1; off < 256; off <<= 1) {
        int add = (t >= off) ? tmp[t - off] : 0;
        __syncthreads();
        tmp[t] += add;
        __syncthreads();
    }
    if (t < kScanNB) bsum[t] = tmp[t] - v;
}

__global__ void k_scan_c(const int* __restrict__ loc, const int* __restrict__ bsum,
                         int* __restrict__ rowptr, int E2) {
    int i = blockIdx.x * kScanB + threadIdx.x;
    if (i < kN) rowptr[i] = loc[i] + bsum[blockIdx.x];
    if (i == 0) rowptr[kN] = E2;
}

// ---- scatter: pure permutation write (4B per edge), no atomic ----
__global__ void k_scatter(const int* __restrict__ ei, int E,
                          const int* __restrict__ rowptr, const int* __restrict__ rank,
                          int* __restrict__ es) {
    int i = blockIdx.x * blockDim.x + threadIdx.x;
    int total = E + kN;
    if (i >= total) return;
    int s, d;
    if (i < E) { s = ei[i]; d = ei[E + i]; } else { s = d = i - E; }
    es[rowptr[d] + rank[i]] = s;
}

// ---- normalized fp16 alpha in CSR order — R16's EXACT version (verified
//      absmax 9.77e-4): two expf passes, alpha computed in fp32, ONE fp16 round.
__global__ __launch_bounds__(256)
void k_wgt(const int* __restrict__ rowptr, const int* __restrict__ es,
           const float* __restrict__ asrc, const float* __restrict__ adst,
           __half* __restrict__ alphaH) {
    const int n = blockIdx.x * 16 + (threadIdx.x >> 4);
    if (n >= kN) return;
    const int l = threadIdx.x & 15;
    const int beg = rowptr[n], end = rowptr[n + 1];
    const float ad0 = adst[n * 4 + 0], ad1 = adst[n * 4 + 1];
    const float ad2 = adst[n * 4 + 2], ad3 = adst[n * 4 + 3];
    float t0 = 0.f, t1 = 0.f, t2 = 0.f, t3 = 0.f;
    for (int p = beg + l; p < end; p += 16) {
        const int s = es[p];
        t0 += expf(lrelu(asrc[s * 4 + 0] + ad0));
        t1 += expf(lrelu(asrc[s * 4 + 1] + ad1));
        t2 += expf(lrelu(asrc[s * 4 + 2] + ad2));
        t3 += expf(lrelu(asrc[s * 4 + 3] + ad3));
    }
#pragma unroll
    for (int off = 8; off >= 1; off >>= 1) {
        t0 += __shfl_xor(t0, off, 64);
        t1 += __shfl_xor(t1, off, 64);
        t2 += __shfl_xor(t2, off, 64);
        t3 += __shfl_xor(t3, off, 64);
    }
    const float r0 = 1.f / t0, r1 = 1.f / t1, r2 = 1.f / t2, r3 = 1.f / t3;
    for (int p = beg + l; p < end; p += 16) {
        const int s = es[p];
        const float w0 = expf(lrelu(asrc[s * 4 + 0] + ad0)) * r0;
        const float w1 = expf(lrelu(asrc[s * 4 + 1] + ad1)) * r1;
        const float w2 = expf(lrelu(asrc[s * 4 + 2] + ad2)) * r2;
        const float w3 = expf(lrelu(asrc[s * 4 + 3] + ad3)) * r3;
        float2 st;
        st.x = pack2h(w0, w1);
        st.y = pack2h(w2, w3);
        *reinterpret_cast<float2*>(&alphaH[(size_t)p * 4]) = st;
    }
}

// ---- layer 1 aggregation (R16 version, best measured 44.4us) ----
__global__ __launch_bounds__(256)
void k_agg1(const int* __restrict__ rowptr, const int* __restrict__ es,
            const __half* __restrict__ alphaH,
            const __half* __restrict__ h1h, const float* __restrict__ b1,
            const float* __restrict__ W2, float* __restrict__ h2) {
    const int n = blockIdx.x * 4 + (threadIdx.x >> 6);
    if (n >= kN) return;
    const int j  = threadIdx.x & 63;
    const int hh = j >> 4;
    const int beg = rowptr[n], end = rowptr[n + 1];
    const __half2* h12 = (const __half2*)h1h;
    __half2 accA = __floats2half2_rn(0.f, 0.f);
    __half2 accB = __floats2half2_rn(0.f, 0.f);
    int p = beg;
    for (; p + 4 <= end; p += 4) {
        const int s0 = es[p],     s1 = es[p + 1];
        const int s2 = es[p + 2], s3 = es[p + 3];
        const __half a0 = alphaH[(size_t)(p + 0) * 4 + hh];
        const __half a1 = alphaH[(size_t)(p + 1) * 4 + hh];
        const __half a2 = alphaH[(size_t)(p + 2) * 4 + hh];
        const __half a3 = alphaH[(size_t)(p + 3) * 4 + hh];
        const __half2 v0 = h12[(size_t)s0 * 64 + j];
        const __half2 v1 = h12[(size_t)s1 * 64 + j];
        const __half2 v2 = h12[(size_t)s2 * 64 + j];
        const __half2 v3 = h12[(size_t)s3 * 64 + j];
        accA = __hfma2(__half2half2(a0), v0, accA);
        accB = __hfma2(__half2half2(a1), v1, accB);
        accA = __hfma2(__half2half2(a2), v2, accA);
        accB = __hfma2(__half2half2(a3), v3, accB);
    }
    for (; p < end; ++p) {
        const int s0 = es[p];
        const __half a0 = alphaH[(size_t)p * 4 + hh];
        accA = __hfma2(__half2half2(a0), h12[(size_t)s0 * 64 + j], accA);
    }
    const float2 fa = __half22float2(accA);
    const float2 fb = __half22float2(accB);
    float vx = fa.x + fb.x;
    float vy = fa.y + fb.y;
    vx += __shfl_xor(vx, 32, 64); vy += __shfl_xor(vy, 32, 64);
    vx += __shfl_xor(vx, 16, 64); vy += __shfl_xor(vy, 16, 64);
    const int m = j & 15;
    float u0 = 0.25f * vx + b1[2 * m];
    float u1 = 0.25f * vy + b1[2 * m + 1];
    u0 = u0 > 0.f ? u0 : expf(u0) - 1.f;
    u1 = u1 > 0.f ? u1 : expf(u1) - 1.f;
    float tsum = u0 * W2[2 * m] + u1 * W2[2 * m + 1];
    tsum += __shfl_xor(tsum, 8, 64);
    tsum += __shfl_xor(tsum, 4, 64);
    tsum += __shfl_xor(tsum, 2, 64);
    tsum += __shfl_xor(tsum, 1, 64);
    if (j == 0) h2[n] = tsum;
}

// ---- layer 2: 16 lanes per node, gather h2 (L2-resident), fused bias -> out ----
__global__ __launch_bounds__(256)
void k_agg2(const int* __restrict__ rowptr, const int* __restrict__ es,
            const float* __restrict__ h2,
            const float* __restrict__ a_s2, const float* __restrict__ a_d2,
            const float* __restrict__ b2, float* __restrict__ out) {
    const int n = blockIdx.x * 16 + (threadIdx.x >> 4);
    if (n >= kN) return;
    const int l = threadIdx.x & 15;
    const float as = a_s2[0], ad = a_d2[0];
    const int beg = rowptr[n], end = rowptr[n + 1];
    const float hd = h2[n] * ad;
    float sw = 0.f, swh = 0.f;
    for (int p = beg + l; p < end; p += 16) {
        float hs = h2[es[p]];
        float w = expf(lrelu(hs * as + hd));
        sw += w;
        swh += w * hs;
    }
#pragma unroll
    for (int off = 8; off >= 1; off >>= 1) {
        sw  += __shfl_xor(sw, off, 64);
        swh += __shfl_xor(swh, off, 64);
    }
    if (l == 0) out[n] = swh / sw + b2[0];
}

extern "C" void kernel_launch(void* const* d_in, const int* in_sizes, int n_in,
                              void* d_out, int out_size, void* d_ws, size_t ws_size,
                              hipStream_t stream) {
    const float* x      = (const float*)d_in[0];
    const int*   ei     = (const int*)d_in[1];
    const float* W1     = (const float*)d_in[3];
    const float* a_src1 = (const float*)d_in[4];
    const float* a_dst1 = (const float*)d_in[5];
    const float* b1     = (const float*)d_in[6];
    const float* W2     = (const float*)d_in[7];
    const float* a_src2 = (const float*)d_in[8];
    const float* a_dst2 = (const float*)d_in[9];
    const float* b2     = (const float*)d_in[10];
    float* out = (float*)d_out;

    const int E  = in_sizes[1] / 2;      // 800000
    const int E2 = E + kN;               // 850000

    // workspace layout (float offsets) — identical to R16
    float*   ws     = (float*)d_ws;
    float*   asrc   = ws;                         //   200,000 f
    float*   adst   = ws + 200000;                //   200,000 f
    float*   h2     = ws + 400000;                //    50,000 f
    __half*  h1h    = (__half*)(ws + 450000);     // 6,400,000 h = 3,200,000 f
    __half*  alphaH = (__half*)(ws + 3650000);    // 3,400,000 h = 1,700,000 f
    int*     ibase  = (int*)(ws + 5350000);
    int*     es     = ibase;                      //   850,000 i
    int*     deg    = ibase + 850000;             //    50,000 i
    int*     rank   = ibase + 900000;             //   850,000 i
    int*     loc    = ibase + 1750000;            //    50,000 i
    int*     rowptr = ibase + 1800000;            //    50,001 i
    int*     bsum   = ibase + 1850016;            //       256 i

    k_init<<<(kN + 255) / 256, 256, 0, stream>>>(deg, kN);

    {
        const int nPass      = (kN + 31) / 32;           // 1563
        const int histBlocks = (E2 + 255) / 256;         // 3321
        k_gemm1_hist<<<kGemmGrid + histBlocks, 256, 0, stream>>>(
            x, W1, h1h, nPass, ei, E, deg, rank);
    }

    k_logits<<<(kN + 3) / 4, 256, 0, stream>>>(h1h, a_src1, a_dst1, asrc, adst);

    k_scan_a<<<kScanNB, kScanB, 0, stream>>>(deg, loc, bsum);
    k_scan_b<<<1, 256, 0, stream>>>(bsum);
    k_scan_c<<<kScanNB, kScanB, 0, stream>>>(loc, bsum, rowptr, E2);

    k_scatter<<<(E2 + 255) / 256, 256, 0, stream>>>(ei, E, rowptr, rank, es);

    k_wgt<<<(kN + 15) / 16, 256, 0, stream>>>(rowptr, es, asrc, adst, alphaH);

    k_agg1<<<(kN + 3) / 4, 256, 0, stream>>>(rowptr, es, alphaH, h1h, b1, W2, h2);

    k_agg2<<<(kN + 15) / 16, 256, 0, stream>>>(rowptr, es, h2, a_src2, a_dst2, b2, out);
}

// Round 21
// 130.733 us; speedup vs baseline: 1.3180x; 1.0528x over previous
//
#include <hip/hip_runtime.h>
#include <hip/hip_fp16.h>
#include <math.h>
#include <stdint.h>

static constexpr int kN     = 50000;
static constexpr int kFIn   = 128;
static constexpr int kHeads = 4;
static constexpr int kScanB = 256;
static constexpr int kScanNB = (kN + kScanB - 1) / kScanB;   // 196
static constexpr int kGemmGrid = 782;                        // gemm-role blocks

typedef _Float16 half8v  __attribute__((ext_vector_type(8)));
typedef float    floatx4 __attribute__((ext_vector_type(4)));

__device__ __forceinline__ float lrelu(float x) { return x > 0.f ? x : 0.2f * x; }

// value-level (address-free) pack of 2 floats -> 2 halves in a float's bits
__device__ __forceinline__ float pack2h(float a, float b) {
    const __half2 h = __floats2half2_rn(a, b);
    return __uint_as_float(__builtin_bit_cast(uint32_t, h));
}

// ---- init: zero deg (must complete before the fat kernel's hist atomics) ----
__global__ void k_init(int* __restrict__ p, int n) {
    int i = blockIdx.x * blockDim.x + threadIdx.x;
    if (i < n) p[i] = 0;
}

// ---- FAT KERNEL 1: blocks [0,kGemmGrid) = MFMA gemm1; rest = hist+rank.
//      (R20 verified: -10us vs separate launches, absmax unchanged.)
__global__ __launch_bounds__(256)
void k_gemm1_hist(const float* __restrict__ x, const float* __restrict__ W1,
                  __half* __restrict__ h1h, int nPass,
                  const int* __restrict__ ei, int E,
                  int* __restrict__ deg, int* __restrict__ rank) {
    __shared__ __align__(16) float whf[128 * 16 * 4];  // 32 KB (fp16 W1, rotated granules)
    __shared__ __align__(16) float xsf[32 * 16 * 4];   //  8 KB (fp16 x tile, rotated granules)

    if (blockIdx.x >= kGemmGrid) {                     // ---- hist role ----
        const int i = (blockIdx.x - kGemmGrid) * 256 + threadIdx.x;
        const int total = E + kN;
        if (i < total) {
            const int d = (i < E) ? ei[E + i] : (i - E);
            rank[i] = atomicAdd(&deg[d], 1);
        }
        return;
    }

    // ---- gemm role (exact R16 k_gemm1) ----
    const int t = threadIdx.x;
    const int l = t & 63;
    const int g = t >> 6;                            // wave 0..3
    for (int idx = t; idx < 2048; idx += 256) {
        const int c = idx >> 7, col = idx & 127;
        float4 st;
        st.x = pack2h(W1[(8 * c + 0) * 128 + col], W1[(8 * c + 1) * 128 + col]);
        st.y = pack2h(W1[(8 * c + 2) * 128 + col], W1[(8 * c + 3) * 128 + col]);
        st.z = pack2h(W1[(8 * c + 4) * 128 + col], W1[(8 * c + 5) * 128 + col]);
        st.w = pack2h(W1[(8 * c + 6) * 128 + col], W1[(8 * c + 7) * 128 + col]);
        const int gran = col * 16 + ((c + col) & 15);
        *reinterpret_cast<float4*>(&whf[gran * 4]) = st;
    }
    __syncthreads();

    const int rt  = g & 1;
    const int ctB = (g >> 1) * 4;
    const int lm  = l & 15;
    const int lk  = l >> 4;

    for (int pass = blockIdx.x; pass < nPass; pass += kGemmGrid) {
        const int nodeBase = pass * 32;
        for (int q = t; q < 512; q += 256) {
            const int nn = q >> 4, ck = q & 15;
            int n = nodeBase + nn; if (n >= kN) n = kN - 1;
            const float4 xa = *reinterpret_cast<const float4*>(&x[(size_t)n * 128 + ck * 8]);
            const float4 xb = *reinterpret_cast<const float4*>(&x[(size_t)n * 128 + ck * 8 + 4]);
            float4 st;
            st.x = pack2h(xa.x, xa.y);
            st.y = pack2h(xa.z, xa.w);
            st.z = pack2h(xb.x, xb.y);
            st.w = pack2h(xb.z, xb.w);
            const int gran = nn * 16 + ((ck + nn) & 15);
            *reinterpret_cast<float4*>(&xsf[gran * 4]) = st;
        }
        __syncthreads();

        floatx4 acc0 = {0.f, 0.f, 0.f, 0.f};
        floatx4 acc1 = {0.f, 0.f, 0.f, 0.f};
        floatx4 acc2 = {0.f, 0.f, 0.f, 0.f};
        floatx4 acc3 = {0.f, 0.f, 0.f, 0.f};
        const int node = rt * 16 + lm;
        const int ch0  = ctB * 16 + lm;
#pragma unroll
        for (int kk = 0; kk < 4; ++kk) {
            const int ck = lk + 4 * kk;
            const half8v af = *reinterpret_cast<const half8v*>(
                &xsf[(node * 16 + ((ck + node) & 15)) * 4]);
            const half8v b0 = *reinterpret_cast<const half8v*>(
                &whf[((ch0 +  0) * 16 + ((ck + ch0 +  0) & 15)) * 4]);
            const half8v b1 = *reinterpret_cast<const half8v*>(
                &whf[((ch0 + 16) * 16 + ((ck + ch0 + 16) & 15)) * 4]);
            const half8v b2 = *reinterpret_cast<const half8v*>(
                &whf[((ch0 + 32) * 16 + ((ck + ch0 + 32) & 15)) * 4]);
            const half8v b3 = *reinterpret_cast<const half8v*>(
                &whf[((ch0 + 48) * 16 + ((ck + ch0 + 48) & 15)) * 4]);
            acc0 = __builtin_amdgcn_mfma_f32_16x16x32_f16(af, b0, acc0, 0, 0, 0);
            acc1 = __builtin_amdgcn_mfma_f32_16x16x32_f16(af, b1, acc1, 0, 0, 0);
            acc2 = __builtin_amdgcn_mfma_f32_16x16x32_f16(af, b2, acc2, 0, 0, 0);
            acc3 = __builtin_amdgcn_mfma_f32_16x16x32_f16(af, b3, acc3, 0, 0, 0);
        }
        // D: col = lm, row = lk*4 + r
        const int nrow0 = nodeBase + rt * 16 + lk * 4;
#pragma unroll
        for (int r = 0; r < 4; ++r) {
            const int n = nrow0 + r;
            if (n < kN) {
                h1h[(size_t)n * 128 + ch0     ] = __float2half(acc0[r]);
                h1h[(size_t)n * 128 + ch0 + 16] = __float2half(acc1[r]);
                h1h[(size_t)n * 128 + ch0 + 32] = __float2half(acc2[r]);
                h1h[(size_t)n * 128 + ch0 + 48] = __float2half(acc3[r]);
            }
        }
        __syncthreads();
    }
}

// ---- FAT KERNEL 2: blocks [0,kScanNB) = scan_a (needs deg); rest = logits
//      (needs h1h). Both inputs complete after k_gemm1_hist; roles independent.
__global__ __launch_bounds__(256)
void k_logits_scana(const __half* __restrict__ h1h,
                    const float* __restrict__ a_src1, const float* __restrict__ a_dst1,
                    float* __restrict__ asrc, float* __restrict__ adst,
                    const int* __restrict__ deg, int* __restrict__ loc,
                    int* __restrict__ bsum) {
    __shared__ int tmp[kScanB];
    if (blockIdx.x < kScanNB) {                      // ---- scan_a role ----
        const int t = threadIdx.x;
        const int i = blockIdx.x * kScanB + t;
        int v = (i < kN) ? deg[i] : 0;
        tmp[t] = v;
        __syncthreads();
        for (int off = 1; off < kScanB; off <<= 1) {
            int add = (t >= off) ? tmp[t - off] : 0;
            __syncthreads();
            tmp[t] += add;
            __syncthreads();
        }
        if (i < kN) loc[i] = tmp[t] - v;             // exclusive within block
        if (t == kScanB - 1) bsum[blockIdx.x] = tmp[t];
        return;
    }
    // ---- logits role (exact R16 k_logits) ----
    const int n = (blockIdx.x - kScanNB) * 4 + (threadIdx.x >> 6);
    if (n >= kN) return;
    const int j = threadIdx.x & 63;
    const float2 f = __half22float2(*(const __half2*)&h1h[(size_t)n * 128 + 2 * j]);
    float ps = f.x * a_src1[2 * j] + f.y * a_src1[2 * j + 1];
    float pd = f.x * a_dst1[2 * j] + f.y * a_dst1[2 * j + 1];
#pragma unroll
    for (int off = 8; off >= 1; off >>= 1) {
        ps += __shfl_xor(ps, off, 64);
        pd += __shfl_xor(pd, off, 64);
    }
    if ((j & 15) == 0) {
        asrc[n * 4 + (j >> 4)] = ps;
        adst[n * 4 + (j >> 4)] = pd;
    }
}

__global__ void k_scan_b(int* __restrict__ bsum) {
    __shared__ int tmp[256];
    int t = threadIdx.x;
    int v = (t < kScanNB) ? bsum[t] : 0;
    tmp[t] = v;
    __syncthreads();
    for (int off = 1; off < 256; off <<= 1) {
        int add = (t >= off) ? tmp[t - off] : 0;
        __syncthreads();
        tmp[t] += add;
        __syncthreads();
    }
    if (t < kScanNB) bsum[t] = tmp[t] - v;
}

__global__ void k_scan_c(const int* __restrict__ loc, const int* __restrict__ bsum,
                         int* __restrict__ rowptr, int E2) {
    int i = blockIdx.x * kScanB + threadIdx.x;
    if (i < kN) rowptr[i] = loc[i] + bsum[blockIdx.x];
    if (i == 0) rowptr[kN] = E2;
}

// ---- scatter: pure permutation write (4B per edge), no atomic ----
__global__ void k_scatter(const int* __restrict__ ei, int E,
                          const int* __restrict__ rowptr, const int* __restrict__ rank,
                          int* __restrict__ es) {
    int i = blockIdx.x * blockDim.x + threadIdx.x;
    int total = E + kN;
    if (i >= total) return;
    int s, d;
    if (i < E) { s = ei[i]; d = ei[E + i]; } else { s = d = i - E; }
    es[rowptr[d] + rank[i]] = s;
}

// ---- normalized fp16 alpha in CSR order — R16's EXACT version (verified) ----
__global__ __launch_bounds__(256)
void k_wgt(const int* __restrict__ rowptr, const int* __restrict__ es,
           const float* __restrict__ asrc, const float* __restrict__ adst,
           __half* __restrict__ alphaH) {
    const int n = blockIdx.x * 16 + (threadIdx.x >> 4);
    if (n >= kN) return;
    const int l = threadIdx.x & 15;
    const int beg = rowptr[n], end = rowptr[n + 1];
    const float ad0 = adst[n * 4 + 0], ad1 = adst[n * 4 + 1];
    const float ad2 = adst[n * 4 + 2], ad3 = adst[n * 4 + 3];
    float t0 = 0.f, t1 = 0.f, t2 = 0.f, t3 = 0.f;
    for (int p = beg + l; p < end; p += 16) {
        const int s = es[p];
        t0 += expf(lrelu(asrc[s * 4 + 0] + ad0));
        t1 += expf(lrelu(asrc[s * 4 + 1] + ad1));
        t2 += expf(lrelu(asrc[s * 4 + 2] + ad2));
        t3 += expf(lrelu(asrc[s * 4 + 3] + ad3));
    }
#pragma unroll
    for (int off = 8; off >= 1; off >>= 1) {
        t0 += __shfl_xor(t0, off, 64);
        t1 += __shfl_xor(t1, off, 64);
        t2 += __shfl_xor(t2, off, 64);
        t3 += __shfl_xor(t3, off, 64);
    }
    const float r0 = 1.f / t0, r1 = 1.f / t1, r2 = 1.f / t2, r3 = 1.f / t3;
    for (int p = beg + l; p < end; p += 16) {
        const int s = es[p];
        const float w0 = expf(lrelu(asrc[s * 4 + 0] + ad0)) * r0;
        const float w1 = expf(lrelu(asrc[s * 4 + 1] + ad1)) * r1;
        const float w2 = expf(lrelu(asrc[s * 4 + 2] + ad2)) * r2;
        const float w3 = expf(lrelu(asrc[s * 4 + 3] + ad3)) * r3;
        float2 st;
        st.x = pack2h(w0, w1);
        st.y = pack2h(w2, w3);
        *reinterpret_cast<float2*>(&alphaH[(size_t)p * 4]) = st;
    }
}

// ---- layer 1 aggregation: unroll-8 (8 gathers in flight) + int32 indexing
//      (R20: 44us at 2.7 TB/s eff; only ~4 loads in flight + 64-bit addr math.
//      Same fp16 alpha*h path and alternating 2-accumulator pairing as R16.)
__global__ __launch_bounds__(256)
void k_agg1(const int* __restrict__ rowptr, const int* __restrict__ es,
            const __half* __restrict__ alphaH,
            const __half* __restrict__ h1h, const float* __restrict__ b1,
            const float* __restrict__ W2, float* __restrict__ h2) {
    const int n = blockIdx.x * 4 + (threadIdx.x >> 6);
    if (n >= kN) return;
    const int j  = threadIdx.x & 63;
    const int hh = j >> 4;
    const int beg = rowptr[n], end = rowptr[n + 1];
    const __half2* h12 = (const __half2*)h1h;
    __half2 accA = __floats2half2_rn(0.f, 0.f);
    __half2 accB = __floats2half2_rn(0.f, 0.f);
    int p = beg;
    for (; p + 8 <= end; p += 8) {
        const int s0 = es[p],     s1 = es[p + 1];
        const int s2 = es[p + 2], s3 = es[p + 3];
        const int s4 = es[p + 4], s5 = es[p + 5];
        const int s6 = es[p + 6], s7 = es[p + 7];
        const __half a0 = alphaH[(p + 0) * 4 + hh];
        const __half a1 = alphaH[(p + 1) * 4 + hh];
        const __half a2 = alphaH[(p + 2) * 4 + hh];
        const __half a3 = alphaH[(p + 3) * 4 + hh];
        const __half a4 = alphaH[(p + 4) * 4 + hh];
        const __half a5 = alphaH[(p + 5) * 4 + hh];
        const __half a6 = alphaH[(p + 6) * 4 + hh];
        const __half a7 = alphaH[(p + 7) * 4 + hh];
        const __half2 v0 = h12[s0 * 64 + j];
        const __half2 v1 = h12[s1 * 64 + j];
        const __half2 v2 = h12[s2 * 64 + j];
        const __half2 v3 = h12[s3 * 64 + j];
        const __half2 v4 = h12[s4 * 64 + j];
        const __half2 v5 = h12[s5 * 64 + j];
        const __half2 v6 = h12[s6 * 64 + j];
        const __half2 v7 = h12[s7 * 64 + j];
        accA = __hfma2(__half2half2(a0), v0, accA);
        accB = __hfma2(__half2half2(a1), v1, accB);
        accA = __hfma2(__half2half2(a2), v2, accA);
        accB = __hfma2(__half2half2(a3), v3, accB);
        accA = __hfma2(__half2half2(a4), v4, accA);
        accB = __hfma2(__half2half2(a5), v5, accB);
        accA = __hfma2(__half2half2(a6), v6, accA);
        accB = __hfma2(__half2half2(a7), v7, accB);
    }
    for (; p + 4 <= end; p += 4) {
        const int s0 = es[p],     s1 = es[p + 1];
        const int s2 = es[p + 2], s3 = es[p + 3];
        const __half a0 = alphaH[(p + 0) * 4 + hh];
        const __half a1 = alphaH[(p + 1) * 4 + hh];
        const __half a2 = alphaH[(p + 2) * 4 + hh];
        const __half a3 = alphaH[(p + 3) * 4 + hh];
        const __half2 v0 = h12[s0 * 64 + j];
        const __half2 v1 = h12[s1 * 64 + j];
        const __half2 v2 = h12[s2 * 64 + j];
        const __half2 v3 = h12[s3 * 64 + j];
        accA = __hfma2(__half2half2(a0), v0, accA);
        accB = __hfma2(__half2half2(a1), v1, accB);
        accA = __hfma2(__half2half2(a2), v2, accA);
        accB = __hfma2(__half2half2(a3), v3, accB);
    }
    for (; p < end; ++p) {
        const int s0 = es[p];
        const __half a0 = alphaH[p * 4 + hh];
        accA = __hfma2(__half2half2(a0), h12[s0 * 64 + j], accA);
    }
    const float2 fa = __half22float2(accA);
    const float2 fb = __half22float2(accB);
    float vx = fa.x + fb.x;
    float vy = fa.y + fb.y;
    vx += __shfl_xor(vx, 32, 64); vy += __shfl_xor(vy, 32, 64);
    vx += __shfl_xor(vx, 16, 64); vy += __shfl_xor(vy, 16, 64);
    const int m = j & 15;
    float u0 = 0.25f * vx + b1[2 * m];
    float u1 = 0.25f * vy + b1[2 * m + 1];
    u0 = u0 > 0.f ? u0 : expf(u0) - 1.f;
    u1 = u1 > 0.f ? u1 : expf(u1) - 1.f;
    float tsum = u0 * W2[2 * m] + u1 * W2[2 * m + 1];
    tsum += __shfl_xor(tsum, 8, 64);
    tsum += __shfl_xor(tsum, 4, 64);
    tsum += __shfl_xor(tsum, 2, 64);
    tsum += __shfl_xor(tsum, 1, 64);
    if (j == 0) h2[n] = tsum;
}

// ---- layer 2: 16 lanes per node, gather h2 (L2-resident), fused bias -> out ----
__global__ __launch_bounds__(256)
void k_agg2(const int* __restrict__ rowptr, const int* __restrict__ es,
            const float* __restrict__ h2,
            const float* __restrict__ a_s2, const float* __restrict__ a_d2,
            const float* __restrict__ b2, float* __restrict__ out) {
    const int n = blockIdx.x * 16 + (threadIdx.x >> 4);
    if (n >= kN) return;
    const int l = threadIdx.x & 15;
    const float as = a_s2[0], ad = a_d2[0];
    const int beg = rowptr[n], end = rowptr[n + 1];
    const float hd = h2[n] * ad;
    float sw = 0.f, swh = 0.f;
    for (int p = beg + l; p < end; p += 16) {
        float hs = h2[es[p]];
        float w = expf(lrelu(hs * as + hd));
        sw += w;
        swh += w * hs;
    }
#pragma unroll
    for (int off = 8; off >= 1; off >>= 1) {
        sw  += __shfl_xor(sw, off, 64);
        swh += __shfl_xor(swh, off, 64);
    }
    if (l == 0) out[n] = swh / sw + b2[0];
}

extern "C" void kernel_launch(void* const* d_in, const int* in_sizes, int n_in,
                              void* d_out, int out_size, void* d_ws, size_t ws_size,
                              hipStream_t stream) {
    const float* x      = (const float*)d_in[0];
    const int*   ei     = (const int*)d_in[1];
    const float* W1     = (const float*)d_in[3];
    const float* a_src1 = (const float*)d_in[4];
    const float* a_dst1 = (const float*)d_in[5];
    const float* b1     = (const float*)d_in[6];
    const float* W2     = (const float*)d_in[7];
    const float* a_src2 = (const float*)d_in[8];
    const float* a_dst2 = (const float*)d_in[9];
    const float* b2     = (const float*)d_in[10];
    float* out = (float*)d_out;

    const int E  = in_sizes[1] / 2;      // 800000
    const int E2 = E + kN;               // 850000

    // workspace layout (float offsets) — identical to R16/R20
    float*   ws     = (float*)d_ws;
    float*   asrc   = ws;                         //   200,000 f
    float*   adst   = ws + 200000;                //   200,000 f
    float*   h2     = ws + 400000;                //    50,000 f
    __half*  h1h    = (__half*)(ws + 450000);     // 6,400,000 h = 3,200,000 f
    __half*  alphaH = (__half*)(ws + 3650000);    // 3,400,000 h = 1,700,000 f
    int*     ibase  = (int*)(ws + 5350000);
    int*     es     = ibase;                      //   850,000 i
    int*     deg    = ibase + 850000;             //    50,000 i
    int*     rank   = ibase + 900000;             //   850,000 i
    int*     loc    = ibase + 1750000;            //    50,000 i
    int*     rowptr = ibase + 1800000;            //    50,001 i
    int*     bsum   = ibase + 1850016;            //       256 i

    k_init<<<(kN + 255) / 256, 256, 0, stream>>>(deg, kN);

    {
        const int nPass      = (kN + 31) / 32;           // 1563
        const int histBlocks = (E2 + 255) / 256;         // 3321
        k_gemm1_hist<<<kGemmGrid + histBlocks, 256, 0, stream>>>(
            x, W1, h1h, nPass, ei, E, deg, rank);
    }

    {
        const int logitBlocks = (kN + 3) / 4;            // 12500
        k_logits_scana<<<kScanNB + logitBlocks, 256, 0, stream>>>(
            h1h, a_src1, a_dst1, asrc, adst, deg, loc, bsum);
    }

    k_scan_b<<<1, 256, 0, stream>>>(bsum);
    k_scan_c<<<kScanNB, kScanB, 0, stream>>>(loc, bsum, rowptr, E2);

    k_scatter<<<(E2 + 255) / 256, 256, 0, stream>>>(ei, E, rowptr, rank, es);

    k_wgt<<<(kN + 15) / 16, 256, 0, stream>>>(rowptr, es, asrc, adst, alphaH);

    k_agg1<<<(kN + 3) / 4, 256, 0, stream>>>(rowptr, es, alphaH, h1h, b1, W2, h2);

    k_agg2<<<(kN + 15) / 16, 256, 0, stream>>>(rowptr, es, h2, a_src2, a_dst2, b2, out);
}